// Round 6
// baseline (262.892 us; speedup 1.0000x reference)
//
#include <hip/hip_runtime.h>
#include <stdint.h>

#define F0    2048      // base input features (= GEMM K)
#define EROWS 512       // embed rows per level
#define NOUT  2048      // output features (= GEMM N)
#define MROWS 8192      // batch (= GEMM M)

typedef __attribute__((ext_vector_type(8))) short bf16x8;
typedef __attribute__((ext_vector_type(4))) float f32x4;
typedef __attribute__((ext_vector_type(8))) unsigned short u16x8;

typedef const __attribute__((address_space(1))) unsigned char ga_t;
typedef __attribute__((address_space(3))) unsigned char lds_t;

__device__ __forceinline__ void async_load16(const void* g, void* l) {
  __builtin_amdgcn_global_load_lds((ga_t*)g, (lds_t*)l, 16, 0, 0);
}

__device__ __forceinline__ unsigned short f2bf(float f) {
  unsigned int u = __builtin_bit_cast(unsigned int, f);
  u += 0x7fffu + ((u >> 16) & 1u);   // round-to-nearest-even
  return (unsigned short)(u >> 16);
}

// ---------------------------------------------------------------------------
// Blocks 0..3: CSR-ize weight b. Blocks 4..2051: x -> bf16 cast.
// ---------------------------------------------------------------------------
__global__ __launch_bounds__(256) void csr_cast_kernel(
    const int* __restrict__ r0, const int* __restrict__ c0, const float* __restrict__ v0, int n0,
    const int* __restrict__ r1, const int* __restrict__ c1, const float* __restrict__ v1, int n1,
    const int* __restrict__ r2, const int* __restrict__ c2, const float* __restrict__ v2, int n2,
    const int* __restrict__ rm, const int* __restrict__ cm, const float* __restrict__ vm, int nm,
    int* __restrict__ rp_all, int* __restrict__ cc_all, float* __restrict__ cv_all,
    const float* __restrict__ x, unsigned short* __restrict__ Ab)
{
  const int b = blockIdx.x;
  const int tid = threadIdx.x;

  if (b >= 4) {
    // ---- x cast: 16,777,216 floats = 2,097,152 vec8; 2048 blocks x 1024 vec8
    const int cb = b - 4;
    const float4* xp = (const float4*)x;
    u16x8* ap = (u16x8*)Ab;
#pragma unroll
    for (int it = 0; it < 4; ++it) {
      int i = cb * 1024 + it * 256 + tid;
      float4 a = xp[2 * i], c = xp[2 * i + 1];
      u16x8 o;
      o[0] = f2bf(a.x); o[1] = f2bf(a.y); o[2] = f2bf(a.z); o[3] = f2bf(a.w);
      o[4] = f2bf(c.x); o[5] = f2bf(c.y); o[6] = f2bf(c.z); o[7] = f2bf(c.w);
      ap[i] = o;
    }
    return;
  }

  // ---- CSR-ize one weight
  const int* rows; const int* cols; const float* vals; int nnz, nrows;
  if      (b == 0) { rows = r0; cols = c0; vals = v0; nnz = n0; nrows = EROWS; }
  else if (b == 1) { rows = r1; cols = c1; vals = v1; nnz = n1; nrows = EROWS; }
  else if (b == 2) { rows = r2; cols = c2; vals = v2; nnz = n2; nrows = EROWS; }
  else             { rows = rm; cols = cm; vals = vm; nnz = nm; nrows = NOUT; }
  int* rp  = rp_all + b * 4096;
  int* cc  = cc_all + b * 8192;          // main (b=3) spills into 16384 entries: region sized for it
  float* cv = cv_all + b * 8192;

  __shared__ int hist[NOUT + 1];
  __shared__ int tsum[256];

  for (int i = tid; i < nrows; i += 256) hist[i] = 0;
  __syncthreads();

  // --- histogram: 8 contiguous entries per thread per round
  int k0 = 0;
  for (; k0 + 2048 <= nnz; k0 += 2048) {
    const int kk = k0 + tid * 8;
    int4 ra = *(const int4*)(rows + kk);
    int4 rb = *(const int4*)(rows + kk + 4);
    atomicAdd(&hist[ra.x], 1); atomicAdd(&hist[ra.y], 1);
    atomicAdd(&hist[ra.z], 1); atomicAdd(&hist[ra.w], 1);
    atomicAdd(&hist[rb.x], 1); atomicAdd(&hist[rb.y], 1);
    atomicAdd(&hist[rb.z], 1); atomicAdd(&hist[rb.w], 1);
  }
  for (int k = k0 + tid; k < nnz; k += 256) atomicAdd(&hist[rows[k]], 1);
  __syncthreads();

  // --- exclusive scan: per-thread partials + parallel Hillis-Steele on 256
  const int per = nrows >> 8;            // 2 or 8
  const int base = tid * per;
  int sum = 0;
  for (int i = 0; i < per; ++i) sum += hist[base + i];
  tsum[tid] = sum;
  __syncthreads();
  for (int off = 1; off < 256; off <<= 1) {
    int add = (tid >= off) ? tsum[tid - off] : 0;
    __syncthreads();
    tsum[tid] += add;
    __syncthreads();
  }
  int run = (tid == 0) ? 0 : tsum[tid - 1];
  for (int i = 0; i < per; ++i) { int h = hist[base + i]; hist[base + i] = run; run += h; }
  __syncthreads();

  for (int i = tid; i < nrows; i += 256) rp[i] = hist[i];
  if (tid == 0) rp[nrows] = nnz;
  __syncthreads();

  // --- scatter: 8 contiguous entries per thread per round (hist = cursors)
  k0 = 0;
  for (; k0 + 2048 <= nnz; k0 += 2048) {
    const int kk = k0 + tid * 8;
    int4   ra = *(const int4*)(rows + kk);
    int4   rb = *(const int4*)(rows + kk + 4);
    int4   ca = *(const int4*)(cols + kk);
    int4   cb2 = *(const int4*)(cols + kk + 4);
    float4 va = *(const float4*)(vals + kk);
    float4 vb = *(const float4*)(vals + kk + 4);
    int p;
    p = atomicAdd(&hist[ra.x], 1); cc[p] = ca.x;  cv[p] = va.x;
    p = atomicAdd(&hist[ra.y], 1); cc[p] = ca.y;  cv[p] = va.y;
    p = atomicAdd(&hist[ra.z], 1); cc[p] = ca.z;  cv[p] = va.z;
    p = atomicAdd(&hist[ra.w], 1); cc[p] = ca.w;  cv[p] = va.w;
    p = atomicAdd(&hist[rb.x], 1); cc[p] = cb2.x; cv[p] = vb.x;
    p = atomicAdd(&hist[rb.y], 1); cc[p] = cb2.y; cv[p] = vb.y;
    p = atomicAdd(&hist[rb.z], 1); cc[p] = cb2.z; cv[p] = vb.z;
    p = atomicAdd(&hist[rb.w], 1); cc[p] = cb2.w; cv[p] = vb.w;
  }
  for (int k = k0 + tid; k < nnz; k += 256) {
    int p = atomicAdd(&hist[rows[k]], 1);
    cc[p] = cols[k]; cv[p] = vals[k];
  }
}

// ---------------------------------------------------------------------------
// One block per MAIN output row r: expand the full recursion tree directly.
// Mb[r][k] (k<F0) = sum over tree paths of prod(vals). Indirect col c>=F0
// refers to e-row (c-F0): level l=(c-F0)>>9 (strictly decreasing along a
// path -> depth <= 3). Block-cooperative BFS: worklist of (row, scale); each
// pop processed by all 256 threads; direct entries scatter-add scalars into
// the 2048-wide LDS row. wl_n snapshot by tid0 + sync -> uniform loop exit.
// Worklist reads clamped to capacity (defensive: a hypothetical overflow
// drops contributions instead of reading garbage -> no OOB global access).
// ---------------------------------------------------------------------------
__global__ __launch_bounds__(256) void expand_tree_kernel(
    const int* __restrict__ rp_all, const int* __restrict__ cc_all,
    const float* __restrict__ cv_all, unsigned short* __restrict__ Mb)
{
  const int r = blockIdx.x;
  const int tid = threadIdx.x;
  __shared__ float acc[F0];
  __shared__ int   wl_row[2048];
  __shared__ float wl_sc[2048];
  __shared__ int   wl_n;
  __shared__ int   wl_snap;

  float4* a4 = (float4*)acc;
  a4[tid * 2]     = (float4){0.f, 0.f, 0.f, 0.f};
  a4[tid * 2 + 1] = (float4){0.f, 0.f, 0.f, 0.f};
  if (tid == 0) wl_n = 0;
  __syncthreads();

  // seed: main CSR row r (weight 3)
  {
    const int* rp3 = rp_all + 3 * 4096;
    const int s = rp3[r], e = rp3[r + 1];
    for (int i = s + tid; i < e; i += 256) {
      int c = cc_all[3 * 8192 + i]; float v = cv_all[3 * 8192 + i];
      if (c < F0) atomicAdd(&acc[c], v);
      else { int p = atomicAdd(&wl_n, 1); if (p < 2048) { wl_row[p] = c - F0; wl_sc[p] = v; } }
    }
  }
  __syncthreads();

  int pos = 0;
  while (true) {
    if (tid == 0) wl_snap = wl_n;
    __syncthreads();
    int nn = wl_snap;                // uniform across block
    if (nn > 2048) nn = 2048;        // clamp to stored capacity (no OOB reads)
    if (pos >= nn) break;
    const int   row = wl_row[pos];
    const float sc  = wl_sc[pos];
    const int l  = row >> 9;         // 0,1,2 (strictly lower level than parent)
    const int lr = row & 511;
    const int* rp = rp_all + l * 4096;
    const int s1 = rp[lr], e1 = rp[lr + 1];
    for (int i = s1 + tid; i < e1; i += 256) {
      int c = cc_all[l * 8192 + i]; float v = sc * cv_all[l * 8192 + i];
      if (c < F0) atomicAdd(&acc[c], v);
      else { int p = atomicAdd(&wl_n, 1); if (p < 2048) { wl_row[p] = c - F0; wl_sc[p] = v; } }
    }
    ++pos;
    __syncthreads();                 // pushes visible before next snapshot
  }

  // write bf16 row
  u16x8 o;
  const float* ap = acc + tid * 8;
  o[0] = f2bf(ap[0]); o[1] = f2bf(ap[1]); o[2] = f2bf(ap[2]); o[3] = f2bf(ap[3]);
  o[4] = f2bf(ap[4]); o[5] = f2bf(ap[5]); o[6] = f2bf(ap[6]); o[7] = f2bf(ap[7]);
  ((u16x8*)Mb)[(size_t)r * 256 + tid] = o;
}

// ---------------------------------------------------------------------------
// C[m,n] = sum_k A[m,k] * B[n,k]   (A: MROWSxK bf16, B: NOUTxK bf16, C fp32)
// 256x256 tile, BK=64, 512 threads = 8 waves (2M x 4N), per-wave 128x64 out.
//
// v5 = v4 (race-fixed read-ahead schedule) + XCD-chunked blockIdx swizzle.
// Without swizzle, flat id mod 8 == bn (gridDim.x=8): each XCD owned ONE bn
// column x ALL 32 bm rows -> streamed the whole 32MB A through its 4MB L2
// (FETCH showed A fetched 4x). Chunked remap nid=(flat&7)*32+(flat>>3) gives
// each XCD bm in [4k,4k+4) x all bn: per-K-tile L2 inbound 1.06MB -> 384KB,
// A fetched once. Bijective (256 % 8 == 0).
//
// Schedule (reads ONE PHASE AHEAD so ds_read clusters overlap MFMA):
//   P1: STG A1(t+1); vm(8);      read bf1(t);            MFMA q00(afP,bf0)
//   P2: BAR;                     read afQ(t);            MFMA q01(afP,bf1)
//   P3: BAR; STG B0(t+2);                                MFMA q10(afQ,bf0)
//   P4: BAR; STG B1(t+2),A0(t+2); vm(6); BAR;
//                                read afP,bf0 (t+1);     MFMA q11(afQ,bf1)
// Region usage is wave-dependent (wr=1 reads only A-half1, wc>=2 only
// B-half1) -> P4's vm(6) forces ALL of tile t+1 incl. A1(t+1) staged this
// tile; prologue vm(6); tail vm(0). All reads anchored at {vmcnt;BAR} pairs.
// ---------------------------------------------------------------------------
__global__ __launch_bounds__(512, 2) void gemm256_kernel(
    const unsigned short* __restrict__ A, const unsigned short* __restrict__ B,
    float* __restrict__ C)
{
  constexpr int K  = F0;        // 2048
  constexpr int N  = NOUT;      // 2048
  constexpr int NT = K / 64;    // 32 K-tiles

  extern __shared__ __align__(16) unsigned short lds[];
  unsigned short* sA = lds;           // [2 buf][2 half][128 rows][64] bf16 = 64 KiB
  unsigned short* sB = lds + 32768;   // same layout = 64 KiB

  const int tid  = threadIdx.x;
  const int lane = tid & 63;
  const int w    = tid >> 6;          // 0..7
  const int wr   = w >> 2;            // 0..1  (M half of the block tile)
  const int wc   = w & 3;             // 0..3  (N quarter)
  const int mm   = lane & 15;
  const int g    = lane >> 4;         // 0..3
  const int sx   = mm & 7;            // per-thread swizzle xor

  // XCD-chunked bijective swizzle: dispatch round-robins flat id across the
  // 8 XCDs; remap so XCD k gets contiguous nid chunk [32k, 32k+32) = bm in
  // [4k,4k+4) x all 8 bn (A panels 4MB/XCD, streamed once).
  const int flat = blockIdx.y * 8 + blockIdx.x;   // gridDim = (8, 32)
  const int nid  = (flat & 7) * 32 + (flat >> 3);
  const int bm   = nid >> 3;          // 0..31
  const int bn   = nid & 7;           // 0..7

  const unsigned short* Ag = A + (size_t)bm * 256 * K;
  const unsigned short* Bg = B + (size_t)bn * 256 * K;

  // staging: thread covers u0=tid (row r0) and u1=512+tid (row 64+r0);
  // LDS dest linear, global source pre-swizzled (both-sides involution).
  const int    r0    = tid >> 3;
  const int    c0    = (tid & 7) ^ (r0 & 7);
  const size_t goff0 = (size_t)r0 * K + c0 * 8;            // elems
  const size_t goff1 = goff0 + (size_t)64 * K;
  const int    loff0 = tid * 8;                            // elems in half region
  const int    loff1 = 4096 + tid * 8;

#define STG(Gb, Sb, buf, h, t) do {                                           \
    async_load16((Gb) + goff0 + (size_t)(h) * 128 * K + (t) * 64,             \
                 (Sb) + (buf) * 16384 + (h) * 8192 + loff0);                  \
    async_load16((Gb) + goff1 + (size_t)(h) * 128 * K + (t) * 64,             \
                 (Sb) + (buf) * 16384 + (h) * 8192 + loff1);                  \
  } while (0)

  // fragment read bases (swizzled slots; frag row & 7 == mm & 7)
  const unsigned short* paB = sA + (wr * 128 + mm) * 64;
  const unsigned short* pbB = sB + (wc * 64  + mm) * 64;
  const int s0 = ((0 * 4 + g) ^ sx) * 8;   // ks=0 slot offset (elems)
  const int s1 = ((1 * 4 + g) ^ sx) * 8;   // ks=1

  bf16x8 afP[4][2];     // A quadrant qm=0 (per-wave: lower 64 rows of wr half)
  bf16x8 afQ[4][2];     // A quadrant qm=1
  bf16x8 bf0[2][2];     // B quadrant qn=0
  bf16x8 bf1[2][2];     // B quadrant qn=1

#define LDA(dst, buf, qm) do {                                                \
    const unsigned short* p_ = paB + (buf) * 16384 + (qm) * 4096;             \
    _Pragma("unroll") for (int tm = 0; tm < 4; ++tm) {                        \
      dst[tm][0] = *(const bf16x8*)(p_ + tm * 1024 + s0);                     \
      dst[tm][1] = *(const bf16x8*)(p_ + tm * 1024 + s1);                     \
    } } while (0)

#define LDB(dst, buf, qn) do {                                                \
    const unsigned short* p_ = pbB + (buf) * 16384 + (qn) * 2048;             \
    _Pragma("unroll") for (int tn = 0; tn < 2; ++tn) {                        \
      dst[tn][0] = *(const bf16x8*)(p_ + tn * 1024 + s0);                     \
      dst[tn][1] = *(const bf16x8*)(p_ + tn * 1024 + s1);                     \
    } } while (0)

#define MFMA_Q(qm, qn, afX, bfX) do {                                         \
    __builtin_amdgcn_s_setprio(1);                                            \
    _Pragma("unroll") for (int tm = 0; tm < 4; ++tm)                          \
    _Pragma("unroll") for (int tn = 0; tn < 2; ++tn) {                        \
      acc[(qm)*4+tm][(qn)*2+tn] = __builtin_amdgcn_mfma_f32_16x16x32_bf16(    \
          afX[tm][0], bfX[tn][0], acc[(qm)*4+tm][(qn)*2+tn], 0, 0, 0);        \
      acc[(qm)*4+tm][(qn)*2+tn] = __builtin_amdgcn_mfma_f32_16x16x32_bf16(    \
          afX[tm][1], bfX[tn][1], acc[(qm)*4+tm][(qn)*2+tn], 0, 0, 0);        \
    }                                                                         \
    __builtin_amdgcn_s_setprio(0);                                            \
  } while (0)

#define CFENCE     asm volatile("" ::: "memory")
#define BAR        do { CFENCE; __builtin_amdgcn_s_barrier(); CFENCE; } while (0)
#define SCHED0     __builtin_amdgcn_sched_barrier(0)
#define WAIT_VM(n) asm volatile("s_waitcnt vmcnt(" #n ")" ::: "memory")

  f32x4 acc[8][4];
#pragma unroll
  for (int i = 0; i < 8; ++i)
#pragma unroll
    for (int j = 0; j < 4; ++j) acc[i][j] = (f32x4)0.f;

  // --- prologue: mimic steady-state issue order so vmcnt counts line up.
  STG(Bg, sB, 0, 0, 0);            // B0(0)
  STG(Bg, sB, 0, 1, 0);            // B1(0)
  STG(Ag, sA, 0, 0, 0);            // A0(0)
  STG(Ag, sA, 0, 1, 0);            // A1(0)
  STG(Bg, sB, 1, 0, 1);            // B0(1)
  STG(Bg, sB, 1, 1, 1);            // B1(1)
  STG(Ag, sA, 1, 0, 1);            // A0(1)
  WAIT_VM(6);                      // forces ALL of tile 0 on THIS wave
  BAR;                             // publication rendezvous block-wide
  SCHED0;
  LDA(afP, 0, 0);
  LDB(bf0, 0, 0);

#pragma unroll 2
  for (int t = 0; t < NT; ++t) {
    const int buf  = t & 1;
    const int nbuf = buf ^ 1;

    // ---- P1 (no barrier: safety anchored at prev tile's P4 {vm;BAR} /
    //      prologue BAR for t=0)
    if (t + 1 < NT) STG(Ag, sA, nbuf, 1, t + 1);   // A1(t+1)
    if (t + 1 < NT) { WAIT_VM(8); } else { WAIT_VM(0); }
    SCHED0;
    LDB(bf1, buf, 1);                              // overlaps q00
    MFMA_Q(0, 0, afP, bf0);

    // ---- P2
    BAR; SCHED0;
    LDA(afQ, buf, 1);                              // overlaps q01
    MFMA_Q(0, 1, afP, bf1);

    // ---- P3
    BAR;
    if (t + 2 < NT) STG(Bg, sB, buf, 0, t + 2);    // B0(t+2): readers done (P2 BAR)
    MFMA_Q(1, 0, afQ, bf0);

    // ---- P4
    BAR;
    if (t + 2 < NT) {
      STG(Bg, sB, buf, 1, t + 2);                  // B1(t+2): free since P3 BAR
      STG(Ag, sA, buf, 0, t + 2);                  // A0(t+2): free since P3 BAR
      WAIT_VM(6);                                  // ALL of tile t+1 landed
      BAR; SCHED0;                                 // publish to all waves
      LDA(afP, nbuf, 0);                           // overlaps q11
      LDB(bf0, nbuf, 0);
    } else if (t + 1 < NT) {
      WAIT_VM(0);                                  // tail: force A1(NT-1) too
      BAR; SCHED0;
      LDA(afP, nbuf, 0);
      LDB(bf0, nbuf, 0);
    }
    MFMA_Q(1, 1, afQ, bf1);
  }

  // --- epilogue: C write (C/D map: col = lane&15, row = g*4 + reg)
  const int rowb = bm * 256 + wr * 128 + g * 4;
  const int colb = bn * 256 + wc * 64 + mm;
#pragma unroll
  for (int im = 0; im < 8; ++im) {
#pragma unroll
    for (int in2 = 0; in2 < 4; ++in2) {
      const int row = rowb + im * 16;
      const int col = colb + in2 * 16;
#pragma unroll
      for (int r = 0; r < 4; ++r)
        C[(size_t)(row + r) * N + col] = acc[im][in2][r];
    }
  }

#undef STG
#undef LDA
#undef LDB
#undef MFMA_Q
#undef CFENCE
#undef BAR
#undef SCHED0
#undef WAIT_VM
}

// ---------------------------------------------------------------------------
extern "C" void kernel_launch(void* const* d_in, const int* in_sizes, int n_in,
                              void* d_out, int out_size, void* d_ws, size_t ws_size,
                              hipStream_t stream)
{
  const float* x   = (const float*)d_in[0];
  const int*   er0 = (const int*)d_in[1];
  const int*   ec0 = (const int*)d_in[2];
  const float* ev0 = (const float*)d_in[3];
  const int*   er1 = (const int*)d_in[4];
  const int*   ec1 = (const int*)d_in[5];
  const float* ev1 = (const float*)d_in[6];
  const int*   er2 = (const int*)d_in[7];
  const int*   ec2 = (const int*)d_in[8];
  const float* ev2 = (const float*)d_in[9];
  const int*   mr  = (const int*)d_in[10];
  const int*   mc  = (const int*)d_in[11];
  const float* mv  = (const float*)d_in[12];
  const int nnz_e0 = in_sizes[1];
  const int nnz_e1 = in_sizes[4];
  const int nnz_e2 = in_sizes[7];
  const int nnz_m  = in_sizes[10];

  int*   rp_all = (int*)d_ws;                              // 4*4096 ints
  int*   cc_all = rp_all + 4 * 4096;                       // 40960 ints used
  float* cv_all = (float*)(cc_all + 48 * 1024);            // 40960 floats used
  float* D      = (float*)(cv_all + 48 * 1024);            // (unused now; layout kept)
  unsigned short* Mb = (unsigned short*)(D + (size_t)3 * EROWS * F0);  // 8 MB
  unsigned short* Ab = Mb + (size_t)NOUT * F0;             // 32 MB

  // 1) CSR-ize all four weights + cast x to bf16 (independent work, one node)
  hipLaunchKernelGGL(csr_cast_kernel, dim3(4 + 2048), dim3(256), 0, stream,
                     er0, ec0, ev0, nnz_e0,
                     er1, ec1, ev1, nnz_e1,
                     er2, ec2, ev2, nnz_e2,
                     mr,  mc,  mv,  nnz_m,
                     rp_all, cc_all, cv_all, x, Ab);

  // 2) expand the full recursion tree directly into Mb (one launch, no D)
  hipLaunchKernelGGL(expand_tree_kernel, dim3(NOUT), dim3(256), 0, stream,
                     rp_all, cc_all, cv_all, Mb);

  // 3) out = x @ M^T  (256^2 read-ahead schedule + XCD swizzle, 128 KiB LDS)
  hipFuncSetAttribute(reinterpret_cast<const void*>(gemm256_kernel),
                      hipFuncAttributeMaxDynamicSharedMemorySize, 131072);
  hipLaunchKernelGGL(gemm256_kernel, dim3(NOUT / 256, MROWS / 256), dim3(512),
                     131072, stream, Ab, Mb, (float*)d_out);
}

// Round 7
// 227.161 us; speedup vs baseline: 1.1573x; 1.1573x over previous
//
#include <hip/hip_runtime.h>
#include <stdint.h>

#define F0    2048      // base input features (= GEMM K)
#define EROWS 512       // embed rows per level
#define NOUT  2048      // output features (= GEMM N)
#define MROWS 8192      // batch (= GEMM M)

typedef __attribute__((ext_vector_type(8))) short bf16x8;
typedef __attribute__((ext_vector_type(4))) float f32x4;
typedef __attribute__((ext_vector_type(8))) unsigned short u16x8;

typedef const __attribute__((address_space(1))) unsigned char ga_t;
typedef __attribute__((address_space(3))) unsigned char lds_t;

__device__ __forceinline__ void async_load16(const void* g, void* l) {
  __builtin_amdgcn_global_load_lds((ga_t*)g, (lds_t*)l, 16, 0, 0);
}

__device__ __forceinline__ unsigned short f2bf(float f) {
  unsigned int u = __builtin_bit_cast(unsigned int, f);
  u += 0x7fffu + ((u >> 16) & 1u);   // round-to-nearest-even
  return (unsigned short)(u >> 16);
}

// ---------------------------------------------------------------------------
// Blocks 0..3: CSR-ize weight b (grid=4; the x-cast rides in the expand
// launches so it overlaps the latency-bound expand chain). [round-4 verbatim]
// ---------------------------------------------------------------------------
__global__ __launch_bounds__(256) void csr_cast_kernel(
    const int* __restrict__ r0, const int* __restrict__ c0, const float* __restrict__ v0, int n0,
    const int* __restrict__ r1, const int* __restrict__ c1, const float* __restrict__ v1, int n1,
    const int* __restrict__ r2, const int* __restrict__ c2, const float* __restrict__ v2, int n2,
    const int* __restrict__ rm, const int* __restrict__ cm, const float* __restrict__ vm, int nm,
    int* __restrict__ rp_all, int* __restrict__ cc_all, float* __restrict__ cv_all)
{
  const int b = blockIdx.x;
  const int tid = threadIdx.x;

  const int* rows; const int* cols; const float* vals; int nnz, nrows;
  if      (b == 0) { rows = r0; cols = c0; vals = v0; nnz = n0; nrows = EROWS; }
  else if (b == 1) { rows = r1; cols = c1; vals = v1; nnz = n1; nrows = EROWS; }
  else if (b == 2) { rows = r2; cols = c2; vals = v2; nnz = n2; nrows = EROWS; }
  else             { rows = rm; cols = cm; vals = vm; nnz = nm; nrows = NOUT; }
  int* rp  = rp_all + b * 4096;
  int* cc  = cc_all + b * 8192;          // main (b=3) spills into 16384 entries: region sized for it
  float* cv = cv_all + b * 8192;

  __shared__ int hist[NOUT + 1];
  __shared__ int tsum[256];

  for (int i = tid; i < nrows; i += 256) hist[i] = 0;
  __syncthreads();

  int k0 = 0;
  for (; k0 + 2048 <= nnz; k0 += 2048) {
    const int kk = k0 + tid * 8;
    int4 ra = *(const int4*)(rows + kk);
    int4 rb = *(const int4*)(rows + kk + 4);
    atomicAdd(&hist[ra.x], 1); atomicAdd(&hist[ra.y], 1);
    atomicAdd(&hist[ra.z], 1); atomicAdd(&hist[ra.w], 1);
    atomicAdd(&hist[rb.x], 1); atomicAdd(&hist[rb.y], 1);
    atomicAdd(&hist[rb.z], 1); atomicAdd(&hist[rb.w], 1);
  }
  for (int k = k0 + tid; k < nnz; k += 256) atomicAdd(&hist[rows[k]], 1);
  __syncthreads();

  const int per = nrows >> 8;            // 2 or 8
  const int base = tid * per;
  int sum = 0;
  for (int i = 0; i < per; ++i) sum += hist[base + i];
  tsum[tid] = sum;
  __syncthreads();
  for (int off = 1; off < 256; off <<= 1) {
    int add = (tid >= off) ? tsum[tid - off] : 0;
    __syncthreads();
    tsum[tid] += add;
    __syncthreads();
  }
  int run = (tid == 0) ? 0 : tsum[tid - 1];
  for (int i = 0; i < per; ++i) { int h = hist[base + i]; hist[base + i] = run; run += h; }
  __syncthreads();

  for (int i = tid; i < nrows; i += 256) rp[i] = hist[i];
  if (tid == 0) rp[nrows] = nnz;
  __syncthreads();

  k0 = 0;
  for (; k0 + 2048 <= nnz; k0 += 2048) {
    const int kk = k0 + tid * 8;
    int4   ra = *(const int4*)(rows + kk);
    int4   rb = *(const int4*)(rows + kk + 4);
    int4   ca = *(const int4*)(cols + kk);
    int4   cb2 = *(const int4*)(cols + kk + 4);
    float4 va = *(const float4*)(vals + kk);
    float4 vb = *(const float4*)(vals + kk + 4);
    int p;
    p = atomicAdd(&hist[ra.x], 1); cc[p] = ca.x;  cv[p] = va.x;
    p = atomicAdd(&hist[ra.y], 1); cc[p] = ca.y;  cv[p] = va.y;
    p = atomicAdd(&hist[ra.z], 1); cc[p] = ca.z;  cv[p] = va.z;
    p = atomicAdd(&hist[ra.w], 1); cc[p] = ca.w;  cv[p] = va.w;
    p = atomicAdd(&hist[rb.x], 1); cc[p] = cb2.x; cv[p] = vb.x;
    p = atomicAdd(&hist[rb.y], 1); cc[p] = cb2.y; cv[p] = vb.y;
    p = atomicAdd(&hist[rb.z], 1); cc[p] = cb2.z; cv[p] = vb.z;
    p = atomicAdd(&hist[rb.w], 1); cc[p] = cb2.w; cv[p] = vb.w;
  }
  for (int k = k0 + tid; k < nnz; k += 256) {
    int p = atomicAdd(&hist[rows[k]], 1);
    cc[p] = cols[k]; cv[p] = vals[k];
  }
}

// ---------------------------------------------------------------------------
// Blocks [0, nrows): one block per dense output row (CSR expand).
// Blocks [nrows, nrows+512): x -> bf16 cast chunk. [round-4 verbatim]
// ---------------------------------------------------------------------------
template <bool BF16OUT>
__global__ __launch_bounds__(256) void expand_csr_kernel(
    const int* __restrict__ rp, const int* __restrict__ cc,
    const float* __restrict__ cv, const float* __restrict__ Dsrc,
    void* __restrict__ out, int nrows,
    const float* __restrict__ x, unsigned short* __restrict__ Ab, int cast_base)
{
  const int b = blockIdx.x;
  const int tid = threadIdx.x;

  if (b >= nrows) {
    const int cb = cast_base + (b - nrows);
    const float4* xp = (const float4*)x;
    u16x8* ap = (u16x8*)Ab;
#pragma unroll
    for (int it = 0; it < 4; ++it) {
      int i = cb * 1024 + it * 256 + tid;
      float4 a = xp[2 * i], c = xp[2 * i + 1];
      u16x8 o;
      o[0] = f2bf(a.x); o[1] = f2bf(a.y); o[2] = f2bf(a.z); o[3] = f2bf(a.w);
      o[4] = f2bf(c.x); o[5] = f2bf(c.y); o[6] = f2bf(c.z); o[7] = f2bf(c.w);
      ap[i] = o;
    }
    return;
  }

  const int r = b;
  __shared__ float acc[F0];
  __shared__ int   icol[128];
  __shared__ float ival[128];
  __shared__ int   icnt;

  float4* a4 = (float4*)acc;
  a4[tid * 2]     = (float4){0.f, 0.f, 0.f, 0.f};
  a4[tid * 2 + 1] = (float4){0.f, 0.f, 0.f, 0.f};
  if (tid == 0) icnt = 0;
  __syncthreads();

  const int s = rp[r], e = rp[r + 1];
  for (int i = s + tid; i < e; i += 256) {
    int c = cc[i]; float v = cv[i];
    if (c < F0) atomicAdd(&acc[c], v);
    else { int p = atomicAdd(&icnt, 1); if (p < 128) { icol[p] = c - F0; ival[p] = v; } }
  }
  __syncthreads();
  int n = icnt; if (n > 128) n = 128;

  float4 q0 = a4[tid * 2], q1 = a4[tid * 2 + 1];
  for (int j = 0; j < n; ++j) {
    const float4* src = (const float4*)(Dsrc + (size_t)icol[j] * F0) + tid * 2;
    float v = ival[j];
    float4 s0 = src[0], s1 = src[1];
    q0.x += v * s0.x; q0.y += v * s0.y; q0.z += v * s0.z; q0.w += v * s0.w;
    q1.x += v * s1.x; q1.y += v * s1.y; q1.z += v * s1.z; q1.w += v * s1.w;
  }

  if (BF16OUT) {
    u16x8 o;
    o[0] = f2bf(q0.x); o[1] = f2bf(q0.y); o[2] = f2bf(q0.z); o[3] = f2bf(q0.w);
    o[4] = f2bf(q1.x); o[5] = f2bf(q1.y); o[6] = f2bf(q1.z); o[7] = f2bf(q1.w);
    ((u16x8*)out)[(size_t)r * 256 + tid] = o;
  } else {
    float4* dst = (float4*)out + (size_t)r * 512 + tid * 2;
    dst[0] = q0; dst[1] = q1;
  }
}

// ---------------------------------------------------------------------------
// GEMM v6: 256x256 tile, BK=64, 8 waves (2Mx4N), XCD swizzle.
// KEY CHANGE vs v4/v5: staging regions re-granulated to match read quadrants:
//   sA buf = [qm][wr][64 rows][64]   (afP reads region qm=0, afQ qm=1 — for
//   sB buf = [qn][wc][32 rows][64]    ALL waves; bf0 reads qn=0, bf1 qn=1)
// -> region usage is wave-INDEPENDENT, enabling a 2-barrier/tile schedule
// with uniform read clusters (4,8,8,4), each {vm;BAR}-anchored and each
// overlapping an MFMA cluster that does not depend on it:
//   P1: STG A1(t+1); read bf1(t);        MFMA q00(afP,bf0)
//   P2: vm(8); BAR;  read afQ(t);        MFMA q01(afP,bf1)
//   P3: STG B0(t+2); vm(2); BAR; read afP(t+1); MFMA q10(afQ,bf1)
//   P4: STG B1,A0(t+2); read bf0(t+1)->alt;     MFMA q11(afQ,bf0)
// vmcnt ledger (2 loads/STG, in-order): entering P1(t) queue =
// [A1(t),B0(t+1),B1(t+1),A0(t+1)] (8). P2: +A1(t+1)=10, vm(8) forces A1(t)
// -> afQ safe. P3: +B0(t+2)=10, vm(2) forces all of t+1 -> afP(t+1) safe;
// P3's own BAR publishes; bf0(t+1) read at P4 also covered. WAR: every
// overwritten region's readers' consuming MFMA precedes the barrier that
// releases the writer (bf0(t) consumed q00@P1 < P2-BAR < STG B0(t+2)@P3;
// bf1(t) consumed q01@P2 < P3-BAR < STG B1(t+2)@P4; afP(t) consumed q01@P2
// < P3-BAR < STG A0(t+2)@P4; A1/B-half regions analogous, 2+ tiles dead).
// bf0 statically ping-ponged (bf0A/bf0B) via unroll-2. Tail pair explicit:
// t=30 {vm(8),vm(2), no B-stage}, t=31 {vm(0) forces A1(31), no stages}.
// ---------------------------------------------------------------------------
__global__ __launch_bounds__(512, 2) void gemm256_kernel(
    const unsigned short* __restrict__ A, const unsigned short* __restrict__ B,
    float* __restrict__ C)
{
  constexpr int K  = F0;        // 2048
  constexpr int N  = NOUT;      // 2048
  constexpr int NT = K / 64;    // 32 K-tiles

  extern __shared__ __align__(16) unsigned short lds[];
  unsigned short* sA = lds;           // [2 buf][qm:2][wr:2][64][64] bf16 = 64 KiB
  unsigned short* sB = lds + 32768;   // [2 buf][qn:2][wc:4][32][64] bf16 = 64 KiB

  const int tid  = threadIdx.x;
  const int lane = tid & 63;
  const int w    = tid >> 6;          // 0..7
  const int wr   = w >> 2;            // 0..1
  const int wc   = w & 3;             // 0..3
  const int mm   = lane & 15;
  const int g    = lane >> 4;         // 0..3
  const int sx   = mm & 7;

  // XCD-chunked bijective swizzle (keeps round-6's FETCH reduction)
  const int flat = blockIdx.y * 8 + blockIdx.x;   // gridDim = (8, 32)
  const int nid  = (flat & 7) * 32 + (flat >> 3);
  const int bm   = nid >> 3;          // 0..31
  const int bn   = nid & 7;           // 0..7

  const unsigned short* Ag = A + (size_t)bm * 256 * K;
  const unsigned short* Bg = B + (size_t)bn * 256 * K;

  // staging addressing: region-linear LDS dest (loff), pre-swizzled global
  // source. r = u>>3 in 0..127 per region; u1 = 512+tid adds +128 src rows
  // for BOTH A and B mappings (verified: (r&63)+(r>>6)*128 and
  // (r&31)+(r>>5)*64 both gain exactly +128 when r += 64).
  const int    r0    = tid >> 3;
  const int    c0    = (tid & 7) ^ (r0 & 7);
  const size_t gA0   = (size_t)((r0 & 63) + (r0 >> 6) * 128) * K + c0 * 8;
  const size_t gB0   = (size_t)((r0 & 31) + (r0 >> 5) * 64)  * K + c0 * 8;
  const int    loff0 = tid * 8;
  const int    loff1 = 4096 + tid * 8;

#define STG_A(buf, qm, t) do {                                                \
    async_load16(Ag + gA0 + (size_t)(qm) * 64 * K + (size_t)(t) * 64,         \
                 sA + (buf) * 16384 + (qm) * 8192 + loff0);                   \
    async_load16(Ag + gA0 + (size_t)(qm) * 64 * K + (size_t)128 * K +         \
                 (size_t)(t) * 64,                                            \
                 sA + (buf) * 16384 + (qm) * 8192 + loff1);                   \
  } while (0)

#define STG_B(buf, qn, t) do {                                                \
    async_load16(Bg + gB0 + (size_t)(qn) * 32 * K + (size_t)(t) * 64,         \
                 sB + (buf) * 16384 + (qn) * 8192 + loff0);                   \
    async_load16(Bg + gB0 + (size_t)(qn) * 32 * K + (size_t)128 * K +         \
                 (size_t)(t) * 64,                                            \
                 sB + (buf) * 16384 + (qn) * 8192 + loff1);                   \
  } while (0)

  // fragment read bases: region row = (wr*64|wc*32)+mm (+tm/tn*16); &7 == mm&7
  const unsigned short* paB = sA + (wr * 64 + mm) * 64;
  const unsigned short* pbB = sB + (wc * 32 + mm) * 64;
  const int s0 = ((0 * 4 + g) ^ sx) * 8;
  const int s1 = ((1 * 4 + g) ^ sx) * 8;

  bf16x8 afP[4][2];     // A region qm=0 of tile t (all waves)
  bf16x8 afQ[4][2];     // A region qm=1
  bf16x8 bf0A[2][2], bf0B[2][2];   // B region qn=0, static ping-pong
  bf16x8 bf1[2][2];     // B region qn=1

#define LDA(dst, buf, qm) do {                                                \
    const unsigned short* p_ = paB + (buf) * 16384 + (qm) * 8192;             \
    _Pragma("unroll") for (int tm = 0; tm < 4; ++tm) {                        \
      dst[tm][0] = *(const bf16x8*)(p_ + tm * 1024 + s0);                     \
      dst[tm][1] = *(const bf16x8*)(p_ + tm * 1024 + s1);                     \
    } } while (0)

#define LDB(dst, buf, qn) do {                                                \
    const unsigned short* p_ = pbB + (buf) * 16384 + (qn) * 8192;             \
    _Pragma("unroll") for (int tn = 0; tn < 2; ++tn) {                        \
      dst[tn][0] = *(const bf16x8*)(p_ + tn * 1024 + s0);                     \
      dst[tn][1] = *(const bf16x8*)(p_ + tn * 1024 + s1);                     \
    } } while (0)

#define MFMA_Q(qm, qn, afX, bfX) do {                                         \
    __builtin_amdgcn_s_setprio(1);                                            \
    _Pragma("unroll") for (int tm = 0; tm < 4; ++tm)                          \
    _Pragma("unroll") for (int tn = 0; tn < 2; ++tn) {                        \
      acc[(qm)*4+tm][(qn)*2+tn] = __builtin_amdgcn_mfma_f32_16x16x32_bf16(    \
          afX[tm][0], bfX[tn][0], acc[(qm)*4+tm][(qn)*2+tn], 0, 0, 0);        \
      acc[(qm)*4+tm][(qn)*2+tn] = __builtin_amdgcn_mfma_f32_16x16x32_bf16(    \
          afX[tm][1], bfX[tn][1], acc[(qm)*4+tm][(qn)*2+tn], 0, 0, 0);        \
    }                                                                         \
    __builtin_amdgcn_s_setprio(0);                                            \
  } while (0)

#define CFENCE     asm volatile("" ::: "memory")
#define BAR        do { CFENCE; __builtin_amdgcn_s_barrier(); CFENCE; } while (0)
#define SCHED0     __builtin_amdgcn_sched_barrier(0)
#define WAIT_VM(n) asm volatile("s_waitcnt vmcnt(" #n ")" ::: "memory")

  f32x4 acc[8][4];
#pragma unroll
  for (int i = 0; i < 8; ++i)
#pragma unroll
    for (int j = 0; j < 4; ++j) acc[i][j] = (f32x4)0.f;

  // --- prologue: queue order B0,B1,A0,A1(0), B0,B1(1), A0(1) = 14 loads.
  STG_B(0, 0, 0); STG_B(0, 1, 0);
  STG_A(0, 0, 0); STG_A(0, 1, 0);
  STG_B(1, 0, 1); STG_B(1, 1, 1);
  STG_A(1, 0, 1);
  WAIT_VM(6);                      // all of tile 0 forced (incl. A1(0))
  BAR; SCHED0;                     // publish block-wide
  LDA(afP, 0, 0);
  LDB(bf0A, 0, 0);

  // one K-tile; BF0C = current bf0 regs, BF0N = next (static ping-pong)
#define TILE(buf, nbuf, BF0C, BF0N, t) do {                                   \
    /* P1 */                                                                  \
    STG_A(nbuf, 1, (t) + 1);                   /* A1(t+1) */                  \
    LDB(bf1, buf, 1);                          /* bf1(t): forced+published */ \
    MFMA_Q(0, 0, afP, BF0C);                                                  \
    /* P2 */                                                                  \
    WAIT_VM(8);                                /* forces A1(t) */             \
    BAR; SCHED0;                                                              \
    LDA(afQ, buf, 1);                                                         \
    MFMA_Q(0, 1, afP, bf1);                                                   \
    /* P3 */                                                                  \
    STG_B(buf, 0, (t) + 2);                    /* B0(t+2): q00 done < P2BAR*/ \
    WAIT_VM(2);                                /* forces ALL of tile t+1 */   \
    BAR; SCHED0;                                                              \
    LDA(afP, nbuf, 0);                         /* afP(t+1) */                 \
    MFMA_Q(1, 1, afQ, bf1);                                                   \
    /* P4 (no barrier) */                                                     \
    STG_B(buf, 1, (t) + 2);                    /* q01 done < P3BAR */         \
    STG_A(buf, 0, (t) + 2);                    /* q01 done < P3BAR */         \
    LDB(BF0N, nbuf, 0);                        /* bf0(t+1): forced@P3 vm */   \
    MFMA_Q(1, 0, afQ, BF0C);                                                  \
  } while (0)

  for (int tp = 0; tp < 15; ++tp) {            // t = 0..29, guard-free
    const int t0 = 2 * tp;
    TILE(0, 1, bf0A, bf0B, t0);
    TILE(1, 0, bf0B, bf0A, t0 + 1);
  }

  // --- t = 30 (buf 0): no B/A stages for t+2=32
  {
    STG_A(1, 1, 31);                           // A1(31)
    LDB(bf1, 0, 1);
    MFMA_Q(0, 0, afP, bf0A);
    WAIT_VM(8); BAR; SCHED0;                   // forces A1(30)
    LDA(afQ, 0, 1);
    MFMA_Q(0, 1, afP, bf1);
    WAIT_VM(2); BAR; SCHED0;                   // queue=[B0,B1,A0,A1](31): forces A0(31)+B(31)
    LDA(afP, 1, 0);                            // afP(31)
    MFMA_Q(1, 1, afQ, bf1);
    LDB(bf0B, 1, 0);                           // bf0(31)
    MFMA_Q(1, 0, afQ, bf0A);
  }
  // --- t = 31 (buf 1): final tile, drain
  {
    LDB(bf1, 1, 1);                            // B1(31) forced @t30-P3 vm(2)
    MFMA_Q(0, 0, afP, bf0B);
    WAIT_VM(0); BAR; SCHED0;                   // forces A1(31) (last 2 loads)
    LDA(afQ, 1, 1);
    MFMA_Q(0, 1, afP, bf1);
    MFMA_Q(1, 1, afQ, bf1);
    MFMA_Q(1, 0, afQ, bf0B);
  }

  // --- epilogue: C write (C/D map: col = lane&15, row = g*4 + reg)
  const int rowb = bm * 256 + wr * 128 + g * 4;
  const int colb = bn * 256 + wc * 64 + mm;
#pragma unroll
  for (int im = 0; im < 8; ++im) {
#pragma unroll
    for (int in2 = 0; in2 < 4; ++in2) {
      const int row = rowb + im * 16;
      const int col = colb + in2 * 16;
#pragma unroll
      for (int r = 0; r < 4; ++r)
        C[(size_t)(row + r) * N + col] = acc[im][in2][r];
    }
  }

#undef STG_A
#undef STG_B
#undef LDA
#undef LDB
#undef MFMA_Q
#undef TILE
#undef CFENCE
#undef BAR
#undef SCHED0
#undef WAIT_VM
}

// ---------------------------------------------------------------------------
extern "C" void kernel_launch(void* const* d_in, const int* in_sizes, int n_in,
                              void* d_out, int out_size, void* d_ws, size_t ws_size,
                              hipStream_t stream)
{
  const float* x   = (const float*)d_in[0];
  const int*   er0 = (const int*)d_in[1];
  const int*   ec0 = (const int*)d_in[2];
  const float* ev0 = (const float*)d_in[3];
  const int*   er1 = (const int*)d_in[4];
  const int*   ec1 = (const int*)d_in[5];
  const float* ev1 = (const float*)d_in[6];
  const int*   er2 = (const int*)d_in[7];
  const int*   ec2 = (const int*)d_in[8];
  const float* ev2 = (const float*)d_in[9];
  const int*   mr  = (const int*)d_in[10];
  const int*   mc  = (const int*)d_in[11];
  const float* mv  = (const float*)d_in[12];
  const int nnz_e0 = in_sizes[1];
  const int nnz_e1 = in_sizes[4];
  const int nnz_e2 = in_sizes[7];
  const int nnz_m  = in_sizes[10];

  int*   rp_all = (int*)d_ws;                              // 4*4096 ints
  int*   cc_all = rp_all + 4 * 4096;                       // 40960 ints used
  float* cv_all = (float*)(cc_all + 48 * 1024);            // 40960 floats used
  float* D      = (float*)(cv_all + 48 * 1024);            // [3*EROWS][F0] fp32 (12 MB)
  unsigned short* Mb = (unsigned short*)(D + (size_t)3 * EROWS * F0);  // 8 MB
  unsigned short* Ab = Mb + (size_t)NOUT * F0;             // 32 MB

  // 1) CSR-ize all four weights (4 blocks; x-cast rides in expand launches)
  hipLaunchKernelGGL(csr_cast_kernel, dim3(4), dim3(256), 0, stream,
                     er0, ec0, ev0, nnz_e0,
                     er1, ec1, ev1, nnz_e1,
                     er2, ec2, ev2, nnz_e2,
                     mr,  mc,  mv,  nnz_m,
                     rp_all, cc_all, cv_all);

  // 2) expand chain (round-4 structure); each launch carries 512 cast blocks
  hipLaunchKernelGGL((expand_csr_kernel<false>), dim3(EROWS + 512), dim3(256), 0, stream,
                     rp_all + 0 * 4096, cc_all + 0 * 8192, cv_all + 0 * 8192,
                     D, (void*)D, EROWS, x, Ab, 0);
  hipLaunchKernelGGL((expand_csr_kernel<false>), dim3(EROWS + 512), dim3(256), 0, stream,
                     rp_all + 1 * 4096, cc_all + 1 * 8192, cv_all + 1 * 8192,
                     D, (void*)(D + (size_t)EROWS * F0), EROWS, x, Ab, 512);
  hipLaunchKernelGGL((expand_csr_kernel<false>), dim3(EROWS + 512), dim3(256), 0, stream,
                     rp_all + 2 * 4096, cc_all + 2 * 8192, cv_all + 2 * 8192,
                     D, (void*)(D + (size_t)2 * EROWS * F0), EROWS, x, Ab, 1024);
  hipLaunchKernelGGL((expand_csr_kernel<true>), dim3(NOUT + 512), dim3(256), 0, stream,
                     rp_all + 3 * 4096, cc_all + 3 * 8192, cv_all + 3 * 8192,
                     D, (void*)Mb, NOUT, x, Ab, 1536);

  // 3) out = x @ M^T  (v6: quadrant-matched regions, 2-barrier/tile, swizzle)
  hipFuncSetAttribute(reinterpret_cast<const void*>(gemm256_kernel),
                      hipFuncAttributeMaxDynamicSharedMemorySize, 131072);
  hipLaunchKernelGGL(gemm256_kernel, dim3(NOUT / 256, MROWS / 256), dim3(512),
                     131072, stream, Ab, Mb, (float*)d_out);
}

// Round 8
// 220.237 us; speedup vs baseline: 1.1937x; 1.0314x over previous
//
#include <hip/hip_runtime.h>
#include <stdint.h>

#define F0    2048      // base input features (= GEMM K)
#define EROWS 512       // embed rows per level
#define NOUT  2048      // output features (= GEMM N)
#define MROWS 8192      // batch (= GEMM M)

typedef __attribute__((ext_vector_type(8))) short bf16x8;
typedef __attribute__((ext_vector_type(4))) float f32x4;
typedef __attribute__((ext_vector_type(8))) unsigned short u16x8;

typedef const __attribute__((address_space(1))) unsigned char ga_t;
typedef __attribute__((address_space(3))) unsigned char lds_t;

__device__ __forceinline__ void async_load16(const void* g, void* l) {
  __builtin_amdgcn_global_load_lds((ga_t*)g, (lds_t*)l, 16, 0, 0);
}

__device__ __forceinline__ unsigned short f2bf(float f) {
  unsigned int u = __builtin_bit_cast(unsigned int, f);
  u += 0x7fffu + ((u >> 16) & 1u);   // round-to-nearest-even
  return (unsigned short)(u >> 16);
}

// ---------------------------------------------------------------------------
// Expand one dense output row per block DIRECTLY FROM COO (no CSR build!).
// Block r scans rows[] with coalesced int4 loads (the 32-64 KB array is
// L2-resident; 8192 entries = 8 rounds of 256 threads). Matches: direct
// (c<F0) -> LDS scatter-add; indirect (c>=F0) -> list, then register AXPY
// against prior dense rows Dsrc[c-F0]. This replaces the 4-block CSR-ize
// kernel (whose single-CU scattered cc/cv stores serialized the chain).
// Blocks [nrows, nrows+512): x -> bf16 cast chunk riding under the latency-
// bound expand (cast_base selects the 512-block chunk).
// ---------------------------------------------------------------------------
template <bool BF16OUT>
__global__ __launch_bounds__(256) void expand_scan_kernel(
    const int* __restrict__ rows, const int* __restrict__ cols,
    const float* __restrict__ vals, int nnz,
    const float* __restrict__ Dsrc, void* __restrict__ out, int nrows,
    const float* __restrict__ x, unsigned short* __restrict__ Ab, int cast_base)
{
  const int b = blockIdx.x;
  const int tid = threadIdx.x;

  if (b >= nrows) {
    // ---- x cast: each block handles 1024 vec8 (8192 floats in, bf16 out)
    const int cb = cast_base + (b - nrows);
    const float4* xp = (const float4*)x;
    u16x8* ap = (u16x8*)Ab;
#pragma unroll
    for (int it = 0; it < 4; ++it) {
      int i = cb * 1024 + it * 256 + tid;
      float4 a = xp[2 * i], c = xp[2 * i + 1];
      u16x8 o;
      o[0] = f2bf(a.x); o[1] = f2bf(a.y); o[2] = f2bf(a.z); o[3] = f2bf(a.w);
      o[4] = f2bf(c.x); o[5] = f2bf(c.y); o[6] = f2bf(c.z); o[7] = f2bf(c.w);
      ap[i] = o;
    }
    return;
  }

  const int r = b;
  __shared__ float acc[F0];
  __shared__ int   icol[128];
  __shared__ float ival[128];
  __shared__ int   icnt;

  float4* a4 = (float4*)acc;
  a4[tid * 2]     = (float4){0.f, 0.f, 0.f, 0.f};
  a4[tid * 2 + 1] = (float4){0.f, 0.f, 0.f, 0.f};
  if (tid == 0) icnt = 0;
  __syncthreads();

  // --- COO scan: coalesced int4 over rows[]; col/val loaded only on match
#define HANDLE(kk) do {                                                       \
    int c_ = cols[kk]; float v_ = vals[kk];                                   \
    if (c_ < F0) atomicAdd(&acc[c_], v_);                                     \
    else { int p_ = atomicAdd(&icnt, 1);                                      \
           if (p_ < 128) { icol[p_] = c_ - F0; ival[p_] = v_; } }             \
  } while (0)

  const int n4 = nnz >> 2;
  for (int gq = tid; gq < n4; gq += 256) {
    const int k = gq * 4;
    int4 rr = *(const int4*)(rows + k);
    if (rr.x == r) HANDLE(k);
    if (rr.y == r) HANDLE(k + 1);
    if (rr.z == r) HANDLE(k + 2);
    if (rr.w == r) HANDLE(k + 3);
  }
  for (int k = (n4 << 2) + tid; k < nnz; k += 256)
    if (rows[k] == r) HANDLE(k);
#undef HANDLE
  __syncthreads();
  int n = icnt; if (n > 128) n = 128;

  float4 q0 = a4[tid * 2], q1 = a4[tid * 2 + 1];
  for (int j = 0; j < n; ++j) {
    const float4* src = (const float4*)(Dsrc + (size_t)icol[j] * F0) + tid * 2;
    float v = ival[j];
    float4 s0 = src[0], s1 = src[1];
    q0.x += v * s0.x; q0.y += v * s0.y; q0.z += v * s0.z; q0.w += v * s0.w;
    q1.x += v * s1.x; q1.y += v * s1.y; q1.z += v * s1.z; q1.w += v * s1.w;
  }

  if (BF16OUT) {
    u16x8 o;
    o[0] = f2bf(q0.x); o[1] = f2bf(q0.y); o[2] = f2bf(q0.z); o[3] = f2bf(q0.w);
    o[4] = f2bf(q1.x); o[5] = f2bf(q1.y); o[6] = f2bf(q1.z); o[7] = f2bf(q1.w);
    ((u16x8*)out)[(size_t)r * 256 + tid] = o;
  } else {
    float4* dst = (float4*)out + (size_t)r * 512 + tid * 2;
    dst[0] = q0; dst[1] = q1;
  }
}

// ---------------------------------------------------------------------------
// GEMM v6 [round-7 verbatim — it just measured 58.7 us / MfmaUtil 46%]:
// 256x256 tile, BK=64, 8 waves (2Mx4N), XCD swizzle, quadrant-matched
// staging regions (sA=[qm][wr][64][64], sB=[qn][wc][32][64]) -> wave-
// independent region usage -> 2-barrier/tile schedule, uniform read
// clusters (4,8,8,4), every read {vm;BAR}-anchored. See round-7 ledger.
// ---------------------------------------------------------------------------
__global__ __launch_bounds__(512, 2) void gemm256_kernel(
    const unsigned short* __restrict__ A, const unsigned short* __restrict__ B,
    float* __restrict__ C)
{
  constexpr int K  = F0;        // 2048
  constexpr int N  = NOUT;      // 2048
  constexpr int NT = K / 64;    // 32 K-tiles

  extern __shared__ __align__(16) unsigned short lds[];
  unsigned short* sA = lds;           // [2 buf][qm:2][wr:2][64][64] bf16 = 64 KiB
  unsigned short* sB = lds + 32768;   // [2 buf][qn:2][wc:4][32][64] bf16 = 64 KiB

  const int tid  = threadIdx.x;
  const int lane = tid & 63;
  const int w    = tid >> 6;          // 0..7
  const int wr   = w >> 2;            // 0..1
  const int wc   = w & 3;             // 0..3
  const int mm   = lane & 15;
  const int g    = lane >> 4;         // 0..3
  const int sx   = mm & 7;

  // XCD-chunked bijective swizzle
  const int flat = blockIdx.y * 8 + blockIdx.x;   // gridDim = (8, 32)
  const int nid  = (flat & 7) * 32 + (flat >> 3);
  const int bm   = nid >> 3;          // 0..31
  const int bn   = nid & 7;           // 0..7

  const unsigned short* Ag = A + (size_t)bm * 256 * K;
  const unsigned short* Bg = B + (size_t)bn * 256 * K;

  const int    r0    = tid >> 3;
  const int    c0    = (tid & 7) ^ (r0 & 7);
  const size_t gA0   = (size_t)((r0 & 63) + (r0 >> 6) * 128) * K + c0 * 8;
  const size_t gB0   = (size_t)((r0 & 31) + (r0 >> 5) * 64)  * K + c0 * 8;
  const int    loff0 = tid * 8;
  const int    loff1 = 4096 + tid * 8;

#define STG_A(buf, qm, t) do {                                                \
    async_load16(Ag + gA0 + (size_t)(qm) * 64 * K + (size_t)(t) * 64,         \
                 sA + (buf) * 16384 + (qm) * 8192 + loff0);                   \
    async_load16(Ag + gA0 + (size_t)(qm) * 64 * K + (size_t)128 * K +         \
                 (size_t)(t) * 64,                                            \
                 sA + (buf) * 16384 + (qm) * 8192 + loff1);                   \
  } while (0)

#define STG_B(buf, qn, t) do {                                                \
    async_load16(Bg + gB0 + (size_t)(qn) * 32 * K + (size_t)(t) * 64,         \
                 sB + (buf) * 16384 + (qn) * 8192 + loff0);                   \
    async_load16(Bg + gB0 + (size_t)(qn) * 32 * K + (size_t)128 * K +         \
                 (size_t)(t) * 64,                                            \
                 sB + (buf) * 16384 + (qn) * 8192 + loff1);                   \
  } while (0)

  const unsigned short* paB = sA + (wr * 64 + mm) * 64;
  const unsigned short* pbB = sB + (wc * 32 + mm) * 64;
  const int s0 = ((0 * 4 + g) ^ sx) * 8;
  const int s1 = ((1 * 4 + g) ^ sx) * 8;

  bf16x8 afP[4][2];
  bf16x8 afQ[4][2];
  bf16x8 bf0A[2][2], bf0B[2][2];
  bf16x8 bf1[2][2];

#define LDA(dst, buf, qm) do {                                                \
    const unsigned short* p_ = paB + (buf) * 16384 + (qm) * 8192;             \
    _Pragma("unroll") for (int tm = 0; tm < 4; ++tm) {                        \
      dst[tm][0] = *(const bf16x8*)(p_ + tm * 1024 + s0);                     \
      dst[tm][1] = *(const bf16x8*)(p_ + tm * 1024 + s1);                     \
    } } while (0)

#define LDB(dst, buf, qn) do {                                                \
    const unsigned short* p_ = pbB + (buf) * 16384 + (qn) * 8192;             \
    _Pragma("unroll") for (int tn = 0; tn < 2; ++tn) {                        \
      dst[tn][0] = *(const bf16x8*)(p_ + tn * 1024 + s0);                     \
      dst[tn][1] = *(const bf16x8*)(p_ + tn * 1024 + s1);                     \
    } } while (0)

#define MFMA_Q(qm, qn, afX, bfX) do {                                         \
    __builtin_amdgcn_s_setprio(1);                                            \
    _Pragma("unroll") for (int tm = 0; tm < 4; ++tm)                          \
    _Pragma("unroll") for (int tn = 0; tn < 2; ++tn) {                        \
      acc[(qm)*4+tm][(qn)*2+tn] = __builtin_amdgcn_mfma_f32_16x16x32_bf16(    \
          afX[tm][0], bfX[tn][0], acc[(qm)*4+tm][(qn)*2+tn], 0, 0, 0);        \
      acc[(qm)*4+tm][(qn)*2+tn] = __builtin_amdgcn_mfma_f32_16x16x32_bf16(    \
          afX[tm][1], bfX[tn][1], acc[(qm)*4+tm][(qn)*2+tn], 0, 0, 0);        \
    }                                                                         \
    __builtin_amdgcn_s_setprio(0);                                            \
  } while (0)

#define CFENCE     asm volatile("" ::: "memory")
#define BAR        do { CFENCE; __builtin_amdgcn_s_barrier(); CFENCE; } while (0)
#define SCHED0     __builtin_amdgcn_sched_barrier(0)
#define WAIT_VM(n) asm volatile("s_waitcnt vmcnt(" #n ")" ::: "memory")

  f32x4 acc[8][4];
#pragma unroll
  for (int i = 0; i < 8; ++i)
#pragma unroll
    for (int j = 0; j < 4; ++j) acc[i][j] = (f32x4)0.f;

  // --- prologue
  STG_B(0, 0, 0); STG_B(0, 1, 0);
  STG_A(0, 0, 0); STG_A(0, 1, 0);
  STG_B(1, 0, 1); STG_B(1, 1, 1);
  STG_A(1, 0, 1);
  WAIT_VM(6);
  BAR; SCHED0;
  LDA(afP, 0, 0);
  LDB(bf0A, 0, 0);

#define TILE(buf, nbuf, BF0C, BF0N, t) do {                                   \
    /* P1 */                                                                  \
    STG_A(nbuf, 1, (t) + 1);                                                  \
    LDB(bf1, buf, 1);                                                         \
    MFMA_Q(0, 0, afP, BF0C);                                                  \
    /* P2 */                                                                  \
    WAIT_VM(8);                                                               \
    BAR; SCHED0;                                                              \
    LDA(afQ, buf, 1);                                                         \
    MFMA_Q(0, 1, afP, bf1);                                                   \
    /* P3 */                                                                  \
    STG_B(buf, 0, (t) + 2);                                                   \
    WAIT_VM(2);                                                               \
    BAR; SCHED0;                                                              \
    LDA(afP, nbuf, 0);                                                        \
    MFMA_Q(1, 1, afQ, bf1);                                                   \
    /* P4 */                                                                  \
    STG_B(buf, 1, (t) + 2);                                                   \
    STG_A(buf, 0, (t) + 2);                                                   \
    LDB(BF0N, nbuf, 0);                                                       \
    MFMA_Q(1, 0, afQ, BF0C);                                                  \
  } while (0)

  for (int tp = 0; tp < 15; ++tp) {            // t = 0..29
    const int t0 = 2 * tp;
    TILE(0, 1, bf0A, bf0B, t0);
    TILE(1, 0, bf0B, bf0A, t0 + 1);
  }

  // --- t = 30
  {
    STG_A(1, 1, 31);
    LDB(bf1, 0, 1);
    MFMA_Q(0, 0, afP, bf0A);
    WAIT_VM(8); BAR; SCHED0;
    LDA(afQ, 0, 1);
    MFMA_Q(0, 1, afP, bf1);
    WAIT_VM(2); BAR; SCHED0;
    LDA(afP, 1, 0);
    MFMA_Q(1, 1, afQ, bf1);
    LDB(bf0B, 1, 0);
    MFMA_Q(1, 0, afQ, bf0A);
  }
  // --- t = 31
  {
    LDB(bf1, 1, 1);
    MFMA_Q(0, 0, afP, bf0B);
    WAIT_VM(0); BAR; SCHED0;
    LDA(afQ, 1, 1);
    MFMA_Q(0, 1, afP, bf1);
    MFMA_Q(1, 1, afQ, bf1);
    MFMA_Q(1, 0, afQ, bf0B);
  }

  // --- epilogue
  const int rowb = bm * 256 + wr * 128 + g * 4;
  const int colb = bn * 256 + wc * 64 + mm;
#pragma unroll
  for (int im = 0; im < 8; ++im) {
#pragma unroll
    for (int in2 = 0; in2 < 4; ++in2) {
      const int row = rowb + im * 16;
      const int col = colb + in2 * 16;
#pragma unroll
      for (int r = 0; r < 4; ++r)
        C[(size_t)(row + r) * N + col] = acc[im][in2][r];
    }
  }

#undef STG_A
#undef STG_B
#undef LDA
#undef LDB
#undef MFMA_Q
#undef TILE
#undef CFENCE
#undef BAR
#undef SCHED0
#undef WAIT_VM
}

// ---------------------------------------------------------------------------
extern "C" void kernel_launch(void* const* d_in, const int* in_sizes, int n_in,
                              void* d_out, int out_size, void* d_ws, size_t ws_size,
                              hipStream_t stream)
{
  const float* x   = (const float*)d_in[0];
  const int*   er0 = (const int*)d_in[1];
  const int*   ec0 = (const int*)d_in[2];
  const float* ev0 = (const float*)d_in[3];
  const int*   er1 = (const int*)d_in[4];
  const int*   ec1 = (const int*)d_in[5];
  const float* ev1 = (const float*)d_in[6];
  const int*   er2 = (const int*)d_in[7];
  const int*   ec2 = (const int*)d_in[8];
  const float* ev2 = (const float*)d_in[9];
  const int*   mr  = (const int*)d_in[10];
  const int*   mc  = (const int*)d_in[11];
  const float* mv  = (const float*)d_in[12];
  const int nnz_e0 = in_sizes[1];
  const int nnz_e1 = in_sizes[4];
  const int nnz_e2 = in_sizes[7];
  const int nnz_m  = in_sizes[10];

  // workspace layout (CSR regions retired but offsets kept stable)
  int*   rp_all = (int*)d_ws;                              // (unused)
  int*   cc_all = rp_all + 4 * 4096;                       // (unused)
  float* cv_all = (float*)(cc_all + 48 * 1024);            // (unused)
  float* D      = (float*)(cv_all + 48 * 1024);            // [3*EROWS][F0] fp32 (12 MB)
  unsigned short* Mb = (unsigned short*)(D + (size_t)3 * EROWS * F0);  // 8 MB
  unsigned short* Ab = Mb + (size_t)NOUT * F0;             // 32 MB

  // 1-4) expand chain directly from COO (no CSR build); each launch also
  // carries 512 x-cast blocks (2048 total)
  hipLaunchKernelGGL((expand_scan_kernel<false>), dim3(EROWS + 512), dim3(256), 0, stream,
                     er0, ec0, ev0, nnz_e0,
                     D, (void*)D, EROWS, x, Ab, 0);
  hipLaunchKernelGGL((expand_scan_kernel<false>), dim3(EROWS + 512), dim3(256), 0, stream,
                     er1, ec1, ev1, nnz_e1,
                     D, (void*)(D + (size_t)EROWS * F0), EROWS, x, Ab, 512);
  hipLaunchKernelGGL((expand_scan_kernel<false>), dim3(EROWS + 512), dim3(256), 0, stream,
                     er2, ec2, ev2, nnz_e2,
                     D, (void*)(D + (size_t)2 * EROWS * F0), EROWS, x, Ab, 1024);
  hipLaunchKernelGGL((expand_scan_kernel<true>), dim3(NOUT + 512), dim3(256), 0, stream,
                     mr, mc, mv, nnz_m,
                     D, (void*)Mb, NOUT, x, Ab, 1536);

  // 5) out = x @ M^T  (round-7 GEMM, unchanged)
  hipFuncSetAttribute(reinterpret_cast<const void*>(gemm256_kernel),
                      hipFuncAttributeMaxDynamicSharedMemorySize, 131072);
  hipLaunchKernelGGL(gemm256_kernel, dim3(NOUT / 256, MROWS / 256), dim3(512),
                     131072, stream, Ab, Mb, (float*)d_out);
}